// Round 11
// baseline (439.271 us; speedup 1.0000x reference)
//
#include <hip/hip_runtime.h>
#include <math.h>

#define BB 16
#define NN 4096
#define SS 8
#define DD 64
#define DHH 128
#define CIN 66
#define NITERS 3
#define LN_EPS_F 1e-5f
#define EPS_ATTN_F 1e-8f
#define QSCALE 0.125f    // d^-0.5
#define LO_SCALE 2048.0f
#define LO_INV 4.8828125e-4f

typedef __attribute__((ext_vector_type(8))) _Float16 half8;
typedef __attribute__((ext_vector_type(4))) _Float16 half4f;
typedef __attribute__((ext_vector_type(4))) float f32x4;
union H8 { half8 v; _Float16 u[8]; };

__device__ __forceinline__ float dot4(float4 a, float4 b) {
    return fmaf(a.x, b.x, fmaf(a.y, b.y, fmaf(a.z, b.z, a.w * b.w)));
}

__device__ __forceinline__ void split_fp16(float z, _Float16& h, _Float16& l) {
    _Float16 hh = (_Float16)z;
    float rem = (z - (float)hh) * LO_SCALE;
    h = hh;
    l = (_Float16)rem;
}

// ---------------------------------------------------------------- init slots
__global__ __launch_bounds__(256) void k_init_slots(
    const float* __restrict__ slots_in, float* __restrict__ slots,
    float* __restrict__ positions, float* __restrict__ scales) {
    int tid = blockIdx.x * 256 + threadIdx.x;
    if (tid < BB * SS * DD) {
        int s = (tid / DD) % SS;
        int c = tid % DD;
        slots[tid] = slots_in[s * 68 + c];
    }
    if (tid < BB * SS * 2) {
        int s = (tid >> 1) & 7;
        int p = tid & 1;
        float po = slots_in[s * 68 + 64 + p];
        positions[tid] = fminf(fmaxf(po, -1.f), 1.f);
        float sc = slots_in[s * 68 + 66 + p];
        scales[tid] = fminf(fmaxf(sc, 1e-3f), 2.f);
    }
}

// ---------------------------------------------------------------- prep W1-derived constants
__global__ __launch_bounds__(256) void k_prep_w(
    const float* __restrict__ W1, const float* __restrict__ lpg,
    const float* __restrict__ lpb, const float* __restrict__ b1,
    const float* __restrict__ Wg,
    float* __restrict__ W1p, float* __restrict__ avec, float* __restrict__ bvec,
    float* __restrict__ s1vec, float* __restrict__ b1p, float* __restrict__ wgc) {
    __shared__ float w1s[128 * 68];
    int tid = threadIdx.x;
    for (int q = 0; q < 8; q++) {
        int flat = q * 1024 + tid * 4;
        int o = flat >> 6, c = flat & 63;
        *(float4*)(w1s + o * 68 + c) = *(const float4*)(W1 + flat);
    }
    __syncthreads();
    if (tid < 128) {
        int o = tid;
        float a = 0.f, bv = 0.f, s1 = 0.f, b1a = b1[o];
        for (int c = 0; c < 64; c++) {
            float w0 = w1s[o * 68 + c];
            float w = w0 * lpg[c];
            W1p[o * 64 + c] = w;
            a = fmaf(w, Wg[2 * c], a);
            bv = fmaf(w, Wg[2 * c + 1], bv);
            s1 += w;
            b1a = fmaf(w0, lpb[c], b1a);
        }
        avec[o] = a; bvec[o] = bv; s1vec[o] = s1; b1p[o] = b1a;
    }
    if (tid == 128) {
        float mwA = 0.f, mwB = 0.f, AA = 0.f, BBv = 0.f, AB = 0.f;
        for (int c = 0; c < 64; c++) {
            float wa = Wg[2 * c], wb = Wg[2 * c + 1];
            mwA += wa; mwB += wb;
            AA = fmaf(wa, wa, AA); BBv = fmaf(wb, wb, BBv); AB = fmaf(wa, wb, AB);
        }
        wgc[0] = mwA * (1.f / 64.f);
        wgc[1] = mwB * (1.f / 64.f);
        wgc[2] = AA * (1.f / 64.f);
        wgc[3] = BBv * (1.f / 64.f);
        wgc[4] = AB * (2.f / 64.f);
    }
}

// ---------------------------------------------------------------- composite weights
__global__ __launch_bounds__(256) void k_prep_w2(
    const float* __restrict__ W1p, const float* __restrict__ Wk,
    const float* __restrict__ Wv, const float* __restrict__ bg,
    float* __restrict__ Wall, float* __restrict__ cu) {
    int flat = blockIdx.x * 256 + threadIdx.x;   // 64 blocks -> 16384
    int mat = flat >> 13, rem = flat & 8191;
    int o = rem >> 6, c = rem & 63;
    const float* Wm = mat ? Wv : Wk;
    float acc = 0.f;
    for (int d = 0; d < 64; d++)
        acc = fmaf(W1p[o * 64 + d], Wm[d * 64 + c], acc);
    Wall[flat] = acc;
    if (flat < 128) {
        float a = 0.f;
        for (int d = 0; d < 64; d++) a = fmaf(W1p[flat * 64 + d], bg[d], a);
        cu[flat] = a;
    }
}

// ---------------------------------------------------------------- W fragments (fp16 hi/lo)
__global__ __launch_bounds__(256) void k_prep_frag(
    const float* __restrict__ Wall, const float* __restrict__ Wk,
    const float* __restrict__ Wv,
    _Float16* __restrict__ cwh, _Float16* __restrict__ cwl,
    _Float16* __restrict__ mwh, _Float16* __restrict__ mwl) {
    int idx = blockIdx.x * 256 + threadIdx.x;    // grid 12 -> 3072
    if (idx < 2048) {
        int f = idx >> 6, lane = idx & 63;       // f = m*16 + ot*2 + ks
        int m = f >> 4, rest = f & 15;
        int ot = rest >> 1, ks = rest & 1;
        int o = ot * 16 + (lane & 15);
        int k0 = ks * 32 + (lane >> 4) * 8;
        const float* src = Wall + m * 8192 + o * 64 + k0;
        #pragma unroll
        for (int j = 0; j < 8; j++) {
            _Float16 h, l;
            split_fp16(src[j], h, l);
            cwh[(size_t)f * 512 + lane * 8 + j] = h;
            cwl[(size_t)f * 512 + lane * 8 + j] = l;
        }
    } else if (idx < 3072) {
        int id2 = idx - 2048;
        int f = id2 >> 6, lane = id2 & 63;       // f = m*8 + ot*2 + ks
        int m = f >> 3, rest = f & 7;
        int ot = rest >> 1, ks = rest & 1;
        int o = ot * 16 + (lane & 15);
        int k0 = ks * 32 + (lane >> 4) * 8;
        const float* src = (m ? Wv : Wk) + o * 64 + k0;
        #pragma unroll
        for (int j = 0; j < 8; j++) {
            _Float16 h, l;
            split_fp16(src[j], h, l);
            mwh[(size_t)f * 512 + lane * 8 + j] = h;
            mwl[(size_t)f * 512 + lane * 8 + j] = l;
        }
    }
}

// ---------------------------------------------------------------- MFMA prep: uk/uv + moments
// grid (1024, 2), 256 thr; no LDS. uk/uv now stored as fp16: halves the
// dominant 7x re-read stream (64MB->32MB working set; per-XCD slice fits L2).
__global__ __launch_bounds__(256) void k_prep_mfma(
    const float* __restrict__ inp,
    const _Float16* __restrict__ cwh, const _Float16* __restrict__ cwl,
    const _Float16* __restrict__ mwh, const _Float16* __restrict__ mwl,
    const float* __restrict__ cu, const float* __restrict__ bg,
    const float* __restrict__ Wg,
    _Float16* __restrict__ uk, _Float16* __restrict__ uv,
    float* __restrict__ kaux, float* __restrict__ vaux, float* __restrict__ gbuf) {
    int tid = threadIdx.x;
    int wv = tid >> 6, lane = tid & 63;
    int quad = lane >> 4, col = lane & 15;
    int mat = blockIdx.y;
    int rowTile = blockIdx.x * 64 + wv * 16;
    half8 ah[2], al[2];
    {
        int rA = rowTile + col;
        const float* rp = inp + (size_t)rA * CIN + quad * 8;
        #pragma unroll
        for (int ks = 0; ks < 2; ks++) {
            H8 h, l;
            #pragma unroll
            for (int q = 0; q < 4; q++) {
                float2 v = *(const float2*)(rp + ks * 32 + 2 * q);
                split_fp16(v.x, h.u[2 * q], l.u[2 * q]);
                split_fp16(v.y, h.u[2 * q + 1], l.u[2 * q + 1]);
            }
            ah[ks] = h.v; al[ks] = l.v;
        }
    }
    const _Float16* cwhm = cwh + (size_t)mat * 16 * 512;
    const _Float16* cwlm = cwl + (size_t)mat * 16 * 512;
    _Float16* dst = mat ? uv : uk;
    _Float16* outb = dst + (size_t)(rowTile + quad * 4) * 128 + col;
    #pragma unroll
    for (int ot = 0; ot < 8; ot++) {
        f32x4 acc1 = {0.f, 0.f, 0.f, 0.f}, acc2 = {0.f, 0.f, 0.f, 0.f};
        #pragma unroll
        for (int ks = 0; ks < 2; ks++) {
            half8 bh = *(const half8*)(cwhm + (size_t)(ot * 2 + ks) * 512 + lane * 8);
            half8 bl = *(const half8*)(cwlm + (size_t)(ot * 2 + ks) * 512 + lane * 8);
            acc1 = __builtin_amdgcn_mfma_f32_16x16x32_f16(ah[ks], bh, acc1, 0, 0, 0);
            acc2 = __builtin_amdgcn_mfma_f32_16x16x32_f16(al[ks], bh, acc2, 0, 0, 0);
            acc2 = __builtin_amdgcn_mfma_f32_16x16x32_f16(ah[ks], bl, acc2, 0, 0, 0);
        }
        float cuv = cu[ot * 16 + col];
        #pragma unroll
        for (int r = 0; r < 4; r++)
            outb[(size_t)r * 128 + ot * 16] =
                (_Float16)(fmaf(acc2[r], LO_INV, acc1[r]) + cuv);
    }
    const _Float16* mwhm = mwh + (size_t)mat * 8 * 512;
    const _Float16* mwlm = mwl + (size_t)mat * 8 * 512;
    float mk[4] = {0.f, 0.f, 0.f, 0.f}, kk2[4] = {0.f, 0.f, 0.f, 0.f};
    float kA[4] = {0.f, 0.f, 0.f, 0.f}, kB[4] = {0.f, 0.f, 0.f, 0.f};
    #pragma unroll
    for (int ot = 0; ot < 4; ot++) {
        f32x4 acc1 = {0.f, 0.f, 0.f, 0.f}, acc2 = {0.f, 0.f, 0.f, 0.f};
        #pragma unroll
        for (int ks = 0; ks < 2; ks++) {
            half8 bh = *(const half8*)(mwhm + (size_t)(ot * 2 + ks) * 512 + lane * 8);
            half8 bl = *(const half8*)(mwlm + (size_t)(ot * 2 + ks) * 512 + lane * 8);
            acc1 = __builtin_amdgcn_mfma_f32_16x16x32_f16(ah[ks], bh, acc1, 0, 0, 0);
            acc2 = __builtin_amdgcn_mfma_f32_16x16x32_f16(al[ks], bh, acc2, 0, 0, 0);
            acc2 = __builtin_amdgcn_mfma_f32_16x16x32_f16(ah[ks], bl, acc2, 0, 0, 0);
        }
        int o = ot * 16 + col;
        float bgo = bg[o], wa = Wg[2 * o], wb = Wg[2 * o + 1];
        #pragma unroll
        for (int r = 0; r < 4; r++) {
            float x = fmaf(acc2[r], LO_INV, acc1[r]) + bgo;
            mk[r] += x; kk2[r] = fmaf(x, x, kk2[r]);
            kA[r] = fmaf(x, wa, kA[r]); kB[r] = fmaf(x, wb, kB[r]);
        }
    }
    #pragma unroll
    for (int off = 1; off <= 8; off <<= 1) {
        #pragma unroll
        for (int r = 0; r < 4; r++) {
            mk[r] += __shfl_xor(mk[r], off, 64);
            kk2[r] += __shfl_xor(kk2[r], off, 64);
            kA[r] += __shfl_xor(kA[r], off, 64);
            kB[r] += __shfl_xor(kB[r], off, 64);
        }
    }
    float* aux = mat ? vaux : kaux;
    if (col == 0) {
        #pragma unroll
        for (int r = 0; r < 4; r++) {
            int row = rowTile + quad * 4 + r;
            float2 g = *(const float2*)(inp + (size_t)row * CIN + 64);
            float4 m1 = {mk[r] * (1.f / 64.f), kk2[r] * (1.f / 64.f),
                         kA[r] * (1.f / 32.f), kB[r] * (1.f / 32.f)};
            float4 m2 = {g.x, g.y, 0.f, 0.f};
            *(float4*)(aux + (size_t)row * 8) = m1;
            *(float4*)(aux + (size_t)row * 8 + 4) = m2;
            if (mat == 0) {
                float2 gw = {g.x, g.y};
                *(float2*)(gbuf + (size_t)row * 2) = gw;
            }
        }
    }
}

// ---------------------------------------------------------------- slot_prep: w2q, qb2
__global__ __launch_bounds__(512) void k_slot_prep(
    const float* __restrict__ slots, const float* __restrict__ lsg,
    const float* __restrict__ lsb, const float* __restrict__ Wq,
    const float* __restrict__ W2, const float* __restrict__ b2,
    float* __restrict__ w2q, float* __restrict__ qb2) {
    __shared__ float sn[512];
    __shared__ float qv[SS][64];
    __shared__ float wsum[8], wsum2[8];
    int b = blockIdx.x, t = threadIdx.x;
    int s = t >> 6, c = t & 63;
    float x = slots[(b * SS + s) * DD + c];
    float sum = x;
    for (int off = 32; off; off >>= 1) sum += __shfl_xor(sum, off, 64);
    float m = sum * (1.f / 64.f);
    float dv = x - m;
    float vs = dv * dv;
    for (int off = 32; off; off >>= 1) vs += __shfl_xor(vs, off, 64);
    float y = dv * rsqrtf(vs * (1.f / 64.f) + LN_EPS_F) * lsg[c] + lsb[c];
    float s1 = y, s2 = y * y;
    for (int off = 32; off; off >>= 1) { s1 += __shfl_xor(s1, off, 64); s2 += __shfl_xor(s2, off, 64); }
    if (c == 0) { wsum[s] = s1; wsum2[s] = s2; }
    __syncthreads();
    float ts1 = 0.f, ts2 = 0.f;
    #pragma unroll
    for (int i = 0; i < 8; i++) { ts1 += wsum[i]; ts2 += wsum2[i]; }
    float gm = ts1 * (1.f / 512.f);
    float gv = ts2 * (1.f / 512.f) - gm * gm;
    sn[t] = (y - gm) * rsqrtf(gv + LN_EPS_F);
    __syncthreads();
    float acc = 0.f;
    for (int j4 = 0; j4 < 64; j4 += 4)
        acc += dot4(*(const float4*)&sn[s * 64 + j4], *(const float4*)(Wq + c * 64 + j4));
    qv[s][c] = acc;
    __syncthreads();
    float a0 = 0.f, a1 = 0.f;
    for (int cc = 0; cc < 64; cc++) {
        float qc = qv[s][cc];
        a0 = fmaf(qc, W2[cc * DHH + c], a0);
        a1 = fmaf(qc, W2[cc * DHH + c + 64], a1);
    }
    w2q[(b * SS + s) * DHH + c] = a0 * QSCALE;
    w2q[(b * SS + s) * DHH + c + 64] = a1 * QSCALE;
    float qb = qv[s][c] * b2[c];
    for (int off = 32; off; off >>= 1) qb += __shfl_xor(qb, off, 64);
    if (c == 0) qb2[b * SS + s] = qb * QSCALE;
}

// ---------------------------------------------------------------- pass1: dots (fp16 uk + depth-2 prefetch)
__global__ __launch_bounds__(256, 4) void k_pass1(
    const _Float16* __restrict__ uk, const float* __restrict__ kaux,
    const float* __restrict__ positions, const float* __restrict__ scales,
    const float* __restrict__ avec, const float* __restrict__ bvec,
    const float* __restrict__ s1vec, const float* __restrict__ b1p,
    const float* __restrict__ wgc, const float* __restrict__ w2q,
    const float* __restrict__ qb2, float* __restrict__ dots) {
    int tid = threadIdx.x;
    int chunk = blockIdx.x, b = blockIdx.y;
    int wv = tid >> 6, lane = tid & 63, rh = lane >> 5, ol = lane & 31;
    int o4 = ol * 4;
    float4 a4 = *(const float4*)(avec + o4);
    float4 bv4 = *(const float4*)(bvec + o4);
    float4 s14 = *(const float4*)(s1vec + o4);
    float4 b14 = *(const float4*)(b1p + o4);
    float mwA = wgc[0], mwB = wgc[1], AA = wgc[2], BBc = wgc[3], AB2 = wgc[4];
    float p0[8], p1[8], rc0[8], rc1[8], qb[8];
    float4 wq[8];
    #pragma unroll
    for (int s = 0; s < 8; s++) {
        int bs = b * 8 + s;
        p0[s] = positions[bs * 2]; p1[s] = positions[bs * 2 + 1];
        rc0[s] = 1.f / scales[bs * 2]; rc1[s] = 1.f / scales[bs * 2 + 1];
        qb[s] = qb2[bs];
        wq[s] = *(const float4*)(w2q + (size_t)bs * DHH + o4);
    }
    int row0 = chunk * 64 + wv * 16 + rh;
    size_t rg = (size_t)b * NN + row0;
    float4 c1 = *(const float4*)(kaux + rg * 8);
    float4 c2 = *(const float4*)(kaux + rg * 8 + 4);
    half4f cu = *(const half4f*)(uk + rg * 128 + o4);
    float4 d1 = *(const float4*)(kaux + (rg + 2) * 8);
    float4 d2 = *(const float4*)(kaux + (rg + 2) * 8 + 4);
    half4f du = *(const half4f*)(uk + (rg + 2) * 128 + o4);
    for (int st = 0; st < 8; st++) {
        float4 e1, e2; half4f eu;
        if (st < 6) {
            size_t rgn = rg + (size_t)(st + 2) * 2;
            e1 = *(const float4*)(kaux + rgn * 8);
            e2 = *(const float4*)(kaux + rgn * 8 + 4);
            eu = *(const half4f*)(uk + rgn * 128 + o4);
        }
        int row = row0 + st * 2;
        float ux = (float)cu.x, uy = (float)cu.y, uz = (float)cu.z, uw = (float)cu.w;
        #pragma unroll
        for (int s = 0; s < 8; s++) {
            float rel0 = (c2.x - p0[s]) * rc0[s];
            float rel1 = (c2.y - p1[s]) * rc1[s];
            float m = fmaf(rel1, mwB, fmaf(rel0, mwA, c1.x));
            float q2 = fmaf(rel0, fmaf(rel0, AA, c1.z), c1.y);
            q2 = fmaf(rel1, fmaf(rel1, BBc, c1.w), q2);
            q2 = fmaf(rel0 * rel1, AB2, q2);
            float var = fmaf(-m, m, q2);
            float rstd = rsqrtf(fmaxf(var, 0.f) + LN_EPS_F);
            float p = 0.f, t, h;
            t = fmaf(-m, s14.x, ux); t = fmaf(rel0, a4.x, t); t = fmaf(rel1, bv4.x, t);
            h = fmaf(rstd, t, b14.x); p = fmaf(fmaxf(h, 0.f), wq[s].x, p);
            t = fmaf(-m, s14.y, uy); t = fmaf(rel0, a4.y, t); t = fmaf(rel1, bv4.y, t);
            h = fmaf(rstd, t, b14.y); p = fmaf(fmaxf(h, 0.f), wq[s].y, p);
            t = fmaf(-m, s14.z, uz); t = fmaf(rel0, a4.z, t); t = fmaf(rel1, bv4.z, t);
            h = fmaf(rstd, t, b14.z); p = fmaf(fmaxf(h, 0.f), wq[s].z, p);
            t = fmaf(-m, s14.w, uw); t = fmaf(rel0, a4.w, t); t = fmaf(rel1, bv4.w, t);
            h = fmaf(rstd, t, b14.w); p = fmaf(fmaxf(h, 0.f), wq[s].w, p);
            p += __shfl_xor(p, 1, 64);
            p += __shfl_xor(p, 2, 64);
            p += __shfl_xor(p, 4, 64);
            p += __shfl_xor(p, 8, 64);
            p += __shfl_xor(p, 16, 64);
            if (ol == 0)
                dots[(size_t)(b * 8 + s) * NN + row] = p + qb[s];
        }
        c1 = d1; c2 = d2; cu = du;
        d1 = e1; d2 = e2; du = eu;
    }
}

// ---------------------------------------------------------------- pass2: H (fp16 uv + depth-2 prefetch)
__global__ __launch_bounds__(256, 4) void k_pass2(
    const _Float16* __restrict__ uv, const float* __restrict__ vaux,
    const float* __restrict__ positions, const float* __restrict__ scales,
    const float* __restrict__ avec, const float* __restrict__ bvec,
    const float* __restrict__ s1vec, const float* __restrict__ b1p,
    const float* __restrict__ wgc, const float* __restrict__ attn,
    float* __restrict__ H) {
    __shared__ float Hw[4 * 1024];
    int tid = threadIdx.x;
    int chunk = blockIdx.x, b = blockIdx.y;
    int wv = tid >> 6, lane = tid & 63, rh = lane >> 5, ol = lane & 31;
    int o4 = ol * 4;
    float4 a4 = *(const float4*)(avec + o4);
    float4 bv4 = *(const float4*)(bvec + o4);
    float4 s14 = *(const float4*)(s1vec + o4);
    float4 b14 = *(const float4*)(b1p + o4);
    float mwA = wgc[0], mwB = wgc[1], AA = wgc[2], BBc = wgc[3], AB2 = wgc[4];
    float p0[8], p1[8], rc0[8], rc1[8];
    #pragma unroll
    for (int s = 0; s < 8; s++) {
        int bs = b * 8 + s;
        p0[s] = positions[bs * 2]; p1[s] = positions[bs * 2 + 1];
        rc0[s] = 1.f / scales[bs * 2]; rc1[s] = 1.f / scales[bs * 2 + 1];
    }
    float hq[8][4];
    #pragma unroll
    for (int s = 0; s < 8; s++)
        #pragma unroll
        for (int c = 0; c < 4; c++) hq[s][c] = 0.f;
    int row0 = chunk * 64 + wv * 16 + rh;
    size_t rg = (size_t)b * NN + row0;
    float4 c1 = *(const float4*)(vaux + rg * 8);
    float4 c2 = *(const float4*)(vaux + rg * 8 + 4);
    half4f cu = *(const half4f*)(uv + rg * 128 + o4);
    float4 d1 = *(const float4*)(vaux + (rg + 2) * 8);
    float4 d2 = *(const float4*)(vaux + (rg + 2) * 8 + 4);
    half4f du = *(const half4f*)(uv + (rg + 2) * 128 + o4);
    for (int st = 0; st < 8; st++) {
        float4 e1, e2; half4f eu;
        if (st < 6) {
            size_t rgn = rg + (size_t)(st + 2) * 2;
            e1 = *(const float4*)(vaux + rgn * 8);
            e2 = *(const float4*)(vaux + rgn * 8 + 4);
            eu = *(const half4f*)(uv + rgn * 128 + o4);
        }
        int row = row0 + st * 2;
        float ux = (float)cu.x, uy = (float)cu.y, uz = (float)cu.z, uw = (float)cu.w;
        #pragma unroll
        for (int s = 0; s < 8; s++) {
            float ar = attn[(size_t)(b * 8 + s) * NN + row];
            float rel0 = (c2.x - p0[s]) * rc0[s];
            float rel1 = (c2.y - p1[s]) * rc1[s];
            float m = fmaf(rel1, mwB, fmaf(rel0, mwA, c1.x));
            float q2 = fmaf(rel0, fmaf(rel0, AA, c1.z), c1.y);
            q2 = fmaf(rel1, fmaf(rel1, BBc, c1.w), q2);
            q2 = fmaf(rel0 * rel1, AB2, q2);
            float var = fmaf(-m, m, q2);
            float rstd = rsqrtf(fmaxf(var, 0.f) + LN_EPS_F);
            float t, h;
            t = fmaf(-m, s14.x, ux); t = fmaf(rel0, a4.x, t); t = fmaf(rel1, bv4.x, t);
            h = fmaf(rstd, t, b14.x); hq[s][0] = fmaf(ar, fmaxf(h, 0.f), hq[s][0]);
            t = fmaf(-m, s14.y, uy); t = fmaf(rel0, a4.y, t); t = fmaf(rel1, bv4.y, t);
            h = fmaf(rstd, t, b14.y); hq[s][1] = fmaf(ar, fmaxf(h, 0.f), hq[s][1]);
            t = fmaf(-m, s14.z, uz); t = fmaf(rel0, a4.z, t); t = fmaf(rel1, bv4.z, t);
            h = fmaf(rstd, t, b14.z); hq[s][2] = fmaf(ar, fmaxf(h, 0.f), hq[s][2]);
            t = fmaf(-m, s14.w, uw); t = fmaf(rel0, a4.w, t); t = fmaf(rel1, bv4.w, t);
            h = fmaf(rstd, t, b14.w); hq[s][3] = fmaf(ar, fmaxf(h, 0.f), hq[s][3]);
        }
        c1 = d1; c2 = d2; cu = du;
        d1 = e1; d2 = e2; du = eu;
    }
    #pragma unroll
    for (int s = 0; s < 8; s++)
        #pragma unroll
        for (int c = 0; c < 4; c++)
            hq[s][c] += __shfl_xor(hq[s][c], 32, 64);
    if (lane < 32) {
        #pragma unroll
        for (int s = 0; s < 8; s++) {
            float4 st = {hq[s][0], hq[s][1], hq[s][2], hq[s][3]};
            *(float4*)(Hw + wv * 1024 + s * 128 + o4) = st;
        }
    }
    __syncthreads();
    #pragma unroll
    for (int q = 0; q < 4; q++) {
        int flat = q * 256 + tid;
        float sum = Hw[flat] + Hw[1024 + flat] + Hw[2048 + flat] + Hw[3072 + flat];
        atomicAdd(&H[(size_t)b * 8 * DHH + flat], sum);
    }
}

// ---------------------------------------------------------------- softmax M,L (+zero H, sacc)
__global__ __launch_bounds__(256) void k_softmax_ms(
    const float* __restrict__ dots, float* __restrict__ Mv, float* __restrict__ Lv,
    float* __restrict__ H, float* __restrict__ sacc) {
    __shared__ float red[4];
    int bs = blockIdx.x, t = threadIdx.x;
    if (t < 128) H[(size_t)bs * DHH + t] = 0.f;
    if (t < 8) sacc[bs * 8 + t] = 0.f;
    const float* dp = dots + (size_t)bs * NN;
    float mx = -1e30f;
    #pragma unroll
    for (int it = 0; it < 4; it++) {
        float4 d = *(const float4*)(dp + it * 1024 + t * 4);
        mx = fmaxf(mx, fmaxf(fmaxf(d.x, d.y), fmaxf(d.z, d.w)));
    }
    for (int off = 32; off; off >>= 1) mx = fmaxf(mx, __shfl_xor(mx, off, 64));
    if ((t & 63) == 0) red[t >> 6] = mx;
    __syncthreads();
    float M = fmaxf(fmaxf(red[0], red[1]), fmaxf(red[2], red[3]));
    __syncthreads();
    float sm = 0.f;
    #pragma unroll
    for (int it = 0; it < 4; it++) {
        float4 d = *(const float4*)(dp + it * 1024 + t * 4);
        sm += __expf(d.x - M) + __expf(d.y - M) + __expf(d.z - M) + __expf(d.w - M);
    }
    for (int off = 32; off; off >>= 1) sm += __shfl_xor(sm, off, 64);
    if ((t & 63) == 0) red[t >> 6] = sm;
    __syncthreads();
    if (t == 0) { Mv[bs] = M; Lv[bs] = red[0] + red[1] + red[2] + red[3]; }
}

// ---------------------------------------------------------------- attn normalize + stats (fused)
template<bool WRITE_ATTN>
__global__ __launch_bounds__(256) void k_attn_stats(
    const float* __restrict__ dots, const float* __restrict__ Mv,
    const float* __restrict__ Lv, const float* __restrict__ gbuf,
    float* __restrict__ attn, float* __restrict__ sacc) {
    __shared__ float red[4][40];
    int chunk = blockIdx.x, b = blockIdx.y;
    int t = threadIdx.x;
    int n = chunk * 256 + t;
    float2 g = *(const float2*)(gbuf + (size_t)(b * NN + n) * 2);
    float gx2 = g.x * g.x, gy2 = g.y * g.y;
    float a[8];
    float rs = 0.f;
    #pragma unroll
    for (int s = 0; s < 8; s++) {
        int bs = b * 8 + s;
        float d = dots[(size_t)bs * NN + n];
        a[s] = __expf(d - Mv[bs]) * (1.f / Lv[bs]) + EPS_ATTN_F;
        rs += a[s];
    }
    float inv = 1.f / rs;
    float v[8][5];
    #pragma unroll
    for (int s = 0; s < 8; s++) {
        float av = a[s] * inv;
        if (WRITE_ATTN)
            attn[(size_t)(b * 8 + s) * NN + n] = av;
        v[s][0] = av;
        v[s][1] = av * g.x;  v[s][2] = av * g.y;
        v[s][3] = av * gx2;  v[s][4] = av * gy2;
    }
    #pragma unroll
    for (int off = 1; off <= 32; off <<= 1)
        #pragma unroll
        for (int s = 0; s < 8; s++)
            #pragma unroll
            for (int j = 0; j < 5; j++)
                v[s][j] += __shfl_xor(v[s][j], off, 64);
    int lane = t & 63, wv = t >> 6;
    if (lane == 0) {
        #pragma unroll
        for (int s = 0; s < 8; s++)
            #pragma unroll
            for (int j = 0; j < 5; j++)
                red[wv][s * 5 + j] = v[s][j];
    }
    __syncthreads();
    if (t < 40) {
        float sum = red[0][t] + red[1][t] + red[2][t] + red[3][t];
        int s = t / 5, j = t % 5;
        atomicAdd(&sacc[(b * 8 + s) * 8 + j], sum);
    }
}

// ---------------------------------------------------------------- GRU + slot MLP (+pos/scale finalize)
__global__ __launch_bounds__(64) void k_gru_mlp(
    const float* __restrict__ H, const float* __restrict__ sacc,
    const float* __restrict__ W2, const float* __restrict__ b2,
    const float* __restrict__ W_ih, const float* __restrict__ W_hh,
    const float* __restrict__ b_ih, const float* __restrict__ b_hh,
    const float* __restrict__ lmg, const float* __restrict__ lmb,
    const float* __restrict__ W3, const float* __restrict__ b3,
    const float* __restrict__ W4, const float* __restrict__ b4,
    float* __restrict__ slots, float* __restrict__ positions,
    float* __restrict__ scales) {
    int bs = blockIdx.x;
    int c = threadIdx.x;
    __shared__ float hl[DHH], ul[DD], sl[DD], yl[DD], hml[DHH];
    float A0 = sacc[bs * 8 + 0];
    if (c < 2) {
        float A1 = sacc[bs * 8 + 1 + c];
        float A2 = sacc[bs * 8 + 3 + c];
        positions[bs * 2 + c] = A1;
        float sx = A2 - A1 * A1 * (2.f - A0);
        scales[bs * 2 + c] = fminf(fmaxf(sqrtf(fmaxf(sx, 0.f)), 1e-3f), 2.f);
    }
    hl[c] = H[bs * DHH + c];
    hl[c + 64] = H[bs * DHH + 64 + c];
    float hold = slots[bs * DD + c];
    sl[c] = hold;
    __syncthreads();
    float u = A0 * b2[c];
    for (int o = 0; o < DHH; o += 4) {
        float4 w = *(const float4*)(W2 + c * DHH + o);
        u = fmaf(w.x, hl[o], fmaf(w.y, hl[o + 1], fmaf(w.z, hl[o + 2], fmaf(w.w, hl[o + 3], u))));
    }
    ul[c] = u;
    __syncthreads();
    float gir = b_ih[c], giz = b_ih[64 + c], gin = b_ih[128 + c];
    float ghr = b_hh[c], ghz = b_hh[64 + c], ghn = b_hh[128 + c];
    for (int k4 = 0; k4 < DD; k4 += 4) {
        float4 uu = *(const float4*)(ul + k4);
        float4 hh = *(const float4*)(sl + k4);
        gir += dot4(uu, *(const float4*)(W_ih + c * DD + k4));
        giz += dot4(uu, *(const float4*)(W_ih + (64 + c) * DD + k4));
        gin += dot4(uu, *(const float4*)(W_ih + (128 + c) * DD + k4));
        ghr += dot4(hh, *(const float4*)(W_hh + c * DD + k4));
        ghz += dot4(hh, *(const float4*)(W_hh + (64 + c) * DD + k4));
        ghn += dot4(hh, *(const float4*)(W_hh + (128 + c) * DD + k4));
    }
    float rg = 1.f / (1.f + __expf(-(gir + ghr)));
    float zg = 1.f / (1.f + __expf(-(giz + ghz)));
    float ng = tanhf(gin + rg * ghn);
    float snew = (1.f - zg) * ng + zg * hold;
    float sum = snew;
    for (int off = 32; off; off >>= 1) sum += __shfl_xor(sum, off, 64);
    float m = sum * (1.f / 64.f);
    float dv = snew - m;
    float vv = dv * dv;
    for (int off = 32; off; off >>= 1) vv += __shfl_xor(vv, off, 64);
    yl[c] = dv * rsqrtf(vv * (1.f / 64.f) + LN_EPS_F) * lmg[c] + lmb[c];
    __syncthreads();
    float h0 = b3[c], h1 = b3[64 + c];
    for (int k4 = 0; k4 < DD; k4 += 4) {
        float4 yy = *(const float4*)(yl + k4);
        h0 += dot4(yy, *(const float4*)(W3 + c * DD + k4));
        h1 += dot4(yy, *(const float4*)(W3 + (64 + c) * DD + k4));
    }
    hml[c] = fmaxf(h0, 0.f);
    hml[64 + c] = fmaxf(h1, 0.f);
    __syncthreads();
    float outv = b4[c];
    for (int o4 = 0; o4 < DHH; o4 += 4) {
        float4 hm4 = *(const float4*)(hml + o4);
        outv += dot4(hm4, *(const float4*)(W4 + c * DHH + o4));
    }
    slots[bs * DD + c] = outv;
}

// ---------------------------------------------------------------- write out (pos/scales from sacc)
__global__ __launch_bounds__(256) void k_write_out(
    const float* __restrict__ slots, const float* __restrict__ sacc,
    float* __restrict__ out) {
    int tid = blockIdx.x * 256 + threadIdx.x;
    if (tid >= BB * SS * 68) return;
    int bs = tid / 68, c = tid % 68;
    float v;
    if (c < 64) {
        v = slots[bs * 64 + c];
    } else if (c < 66) {
        v = sacc[bs * 8 + 1 + (c - 64)];
    } else {
        int p = c - 66;
        float A0 = sacc[bs * 8 + 0];
        float A1 = sacc[bs * 8 + 1 + p];
        float A2 = sacc[bs * 8 + 3 + p];
        float sx = A2 - A1 * A1 * (2.f - A0);
        v = fminf(fmaxf(sqrtf(fmaxf(sx, 0.f)), 1e-3f), 2.f);
    }
    out[tid] = v;
}

// ---------------------------------------------------------------- launcher
extern "C" void kernel_launch(void* const* d_in, const int* in_sizes, int n_in,
                              void* d_out, int out_size, void* d_ws, size_t ws_size,
                              hipStream_t stream) {
    (void)in_sizes; (void)n_in; (void)out_size; (void)ws_size;
    const float* inp = (const float*)d_in[0];
    const float* slots_in = (const float*)d_in[1];
    const float* Wq = (const float*)d_in[2];
    const float* Wk = (const float*)d_in[3];
    const float* Wv = (const float*)d_in[4];
    const float* Wg = (const float*)d_in[5];
    const float* bg = (const float*)d_in[6];
    const float* lpg = (const float*)d_in[7];
    const float* lpb = (const float*)d_in[8];
    const float* W1 = (const float*)d_in[9];
    const float* b1 = (const float*)d_in[10];
    const float* W2 = (const float*)d_in[11];
    const float* b2 = (const float*)d_in[12];
    const float* W_ih = (const float*)d_in[13];
    const float* W_hh = (const float*)d_in[14];
    const float* b_ih = (const float*)d_in[15];
    const float* b_hh = (const float*)d_in[16];
    const float* lmg = (const float*)d_in[17];
    const float* lmb = (const float*)d_in[18];
    const float* W3 = (const float*)d_in[19];
    const float* b3 = (const float*)d_in[20];
    const float* W4 = (const float*)d_in[21];
    const float* b4 = (const float*)d_in[22];
    const float* lsg = (const float*)d_in[23];
    const float* lsb = (const float*)d_in[24];
    float* out = (float*)d_out;
    float* ws = (float*)d_ws;

    const size_t NR = (size_t)BB * NN;
    size_t o_uk = 0;                       // fp16: NR*128 halfs = NR*64 floats
    size_t o_uv = o_uk + NR * 64;
    size_t o_kaux = o_uv + NR * 64;
    size_t o_vaux = o_kaux + NR * 8;
    size_t o_gbuf = o_vaux + NR * 8;
    size_t o_dots = o_gbuf + NR * 2;
    size_t o_attn = o_dots + NR * SS;
    size_t o_slots = o_attn + NR * SS;
    size_t o_pos = o_slots + BB * SS * DD;
    size_t o_scl = o_pos + BB * SS * 2;
    size_t o_w2q = o_scl + BB * SS * 2;
    size_t o_qb2 = o_w2q + BB * SS * DHH;
    size_t o_Mv = o_qb2 + BB * SS;
    size_t o_Lv = o_Mv + BB * SS;
    size_t o_H = o_Lv + BB * SS;
    size_t o_sacc = o_H + BB * SS * DHH;
    size_t o_W1p = o_sacc + BB * SS * 8;
    size_t o_avec = o_W1p + DHH * DD;
    size_t o_bvec = o_avec + DHH;
    size_t o_s1v = o_bvec + DHH;
    size_t o_b1p = o_s1v + DHH;
    size_t o_wgc = o_b1p + DHH;
    size_t o_Wall = o_wgc + 8;
    size_t o_cu = o_Wall + 2 * DHH * DD;
    size_t o_cwh = o_cu + DHH;            // 2*16*512 halfs = 8192 floats
    size_t o_cwl = o_cwh + 8192;
    size_t o_mwh = o_cwl + 8192;          // 2*8*512 halfs = 4096 floats
    size_t o_mwl = o_mwh + 4096;

    _Float16* uk = (_Float16*)(ws + o_uk);
    _Float16* uv = (_Float16*)(ws + o_uv);
    float* kaux = ws + o_kaux;
    float* vaux = ws + o_vaux;
    float* gbuf = ws + o_gbuf;
    float* dots = ws + o_dots;
    float* attn = ws + o_attn;
    float* slots = ws + o_slots;
    float* positions = ws + o_pos;
    float* scales = ws + o_scl;
    float* w2q = ws + o_w2q;
    float* qb2 = ws + o_qb2;
    float* Mv = ws + o_Mv;
    float* Lv = ws + o_Lv;
    float* H = ws + o_H;
    float* sacc = ws + o_sacc;
    float* W1p = ws + o_W1p;
    float* avec = ws + o_avec;
    float* bvec = ws + o_bvec;
    float* s1v = ws + o_s1v;
    float* b1p = ws + o_b1p;
    float* wgc = ws + o_wgc;
    float* Wall = ws + o_Wall;
    float* cu = ws + o_cu;
    _Float16* cwh = (_Float16*)(ws + o_cwh);
    _Float16* cwl = (_Float16*)(ws + o_cwl);
    _Float16* mwh = (_Float16*)(ws + o_mwh);
    _Float16* mwl = (_Float16*)(ws + o_mwl);

    k_init_slots<<<32, 256, 0, stream>>>(slots_in, slots, positions, scales);
    k_prep_w<<<1, 256, 0, stream>>>(W1, lpg, lpb, b1, Wg, W1p, avec, bvec, s1v, b1p, wgc);
    k_prep_w2<<<64, 256, 0, stream>>>(W1p, Wk, Wv, bg, Wall, cu);
    k_prep_frag<<<12, 256, 0, stream>>>(Wall, Wk, Wv, cwh, cwl, mwh, mwl);
    k_prep_mfma<<<dim3(1024, 2), 256, 0, stream>>>(inp, cwh, cwl, mwh, mwl,
                                                   cu, bg, Wg, uk, uv, kaux, vaux, gbuf);

    for (int it = 0; it <= NITERS; ++it) {
        k_slot_prep<<<BB, 512, 0, stream>>>(slots, lsg, lsb, Wq, W2, b2, w2q, qb2);
        k_pass1<<<dim3(64, BB), 256, 0, stream>>>(uk, kaux, positions, scales,
                                                  avec, bvec, s1v, b1p, wgc, w2q, qb2, dots);
        k_softmax_ms<<<BB * SS, 256, 0, stream>>>(dots, Mv, Lv, H, sacc);
        if (it < NITERS) {
            k_attn_stats<true><<<dim3(16, BB), 256, 0, stream>>>(dots, Mv, Lv, gbuf, attn, sacc);
            k_pass2<<<dim3(64, BB), 256, 0, stream>>>(uv, vaux, positions, scales,
                                                      avec, bvec, s1v, b1p, wgc, attn, H);
            k_gru_mlp<<<BB * SS, 64, 0, stream>>>(H, sacc, W2, b2, W_ih, W_hh, b_ih, b_hh,
                                                  lmg, lmb, W3, b3, W4, b4,
                                                  slots, positions, scales);
        } else {
            k_attn_stats<false><<<dim3(16, BB), 256, 0, stream>>>(dots, Mv, Lv, gbuf, attn, sacc);
        }
    }
    k_write_out<<<34, 256, 0, stream>>>(slots, sacc, out);
}

// Round 12
// 433.369 us; speedup vs baseline: 1.0136x; 1.0136x over previous
//
#include <hip/hip_runtime.h>
#include <math.h>

#define BB 16
#define NN 4096
#define SS 8
#define DD 64
#define DHH 128
#define CIN 66
#define NITERS 3
#define LN_EPS_F 1e-5f
#define EPS_ATTN_F 1e-8f
#define QSCALE 0.125f    // d^-0.5
#define LO_SCALE 2048.0f
#define LO_INV 4.8828125e-4f

typedef __attribute__((ext_vector_type(8))) _Float16 half8;
typedef __attribute__((ext_vector_type(4))) float f32x4;
union H8 { half8 v; _Float16 u[8]; };

__device__ __forceinline__ float dot4(float4 a, float4 b) {
    return fmaf(a.x, b.x, fmaf(a.y, b.y, fmaf(a.z, b.z, a.w * b.w)));
}

__device__ __forceinline__ void split_fp16(float z, _Float16& h, _Float16& l) {
    _Float16 hh = (_Float16)z;
    float rem = (z - (float)hh) * LO_SCALE;
    h = hh;
    l = (_Float16)rem;
}

// ---------------------------------------------------------------- init slots
__global__ __launch_bounds__(256) void k_init_slots(
    const float* __restrict__ slots_in, float* __restrict__ slots,
    float* __restrict__ positions, float* __restrict__ scales) {
    int tid = blockIdx.x * 256 + threadIdx.x;
    if (tid < BB * SS * DD) {
        int s = (tid / DD) % SS;
        int c = tid % DD;
        slots[tid] = slots_in[s * 68 + c];
    }
    if (tid < BB * SS * 2) {
        int s = (tid >> 1) & 7;
        int p = tid & 1;
        float po = slots_in[s * 68 + 64 + p];
        positions[tid] = fminf(fmaxf(po, -1.f), 1.f);
        float sc = slots_in[s * 68 + 66 + p];
        scales[tid] = fminf(fmaxf(sc, 1e-3f), 2.f);
    }
}

// ---------------------------------------------------------------- prep W1-derived constants
__global__ __launch_bounds__(256) void k_prep_w(
    const float* __restrict__ W1, const float* __restrict__ lpg,
    const float* __restrict__ lpb, const float* __restrict__ b1,
    const float* __restrict__ Wg,
    float* __restrict__ W1p, float* __restrict__ avec, float* __restrict__ bvec,
    float* __restrict__ s1vec, float* __restrict__ b1p, float* __restrict__ wgc) {
    __shared__ float w1s[128 * 68];
    int tid = threadIdx.x;
    for (int q = 0; q < 8; q++) {
        int flat = q * 1024 + tid * 4;
        int o = flat >> 6, c = flat & 63;
        *(float4*)(w1s + o * 68 + c) = *(const float4*)(W1 + flat);
    }
    __syncthreads();
    if (tid < 128) {
        int o = tid;
        float a = 0.f, bv = 0.f, s1 = 0.f, b1a = b1[o];
        for (int c = 0; c < 64; c++) {
            float w0 = w1s[o * 68 + c];
            float w = w0 * lpg[c];
            W1p[o * 64 + c] = w;
            a = fmaf(w, Wg[2 * c], a);
            bv = fmaf(w, Wg[2 * c + 1], bv);
            s1 += w;
            b1a = fmaf(w0, lpb[c], b1a);
        }
        avec[o] = a; bvec[o] = bv; s1vec[o] = s1; b1p[o] = b1a;
    }
    if (tid == 128) {
        float mwA = 0.f, mwB = 0.f, AA = 0.f, BBv = 0.f, AB = 0.f;
        for (int c = 0; c < 64; c++) {
            float wa = Wg[2 * c], wb = Wg[2 * c + 1];
            mwA += wa; mwB += wb;
            AA = fmaf(wa, wa, AA); BBv = fmaf(wb, wb, BBv); AB = fmaf(wa, wb, AB);
        }
        wgc[0] = mwA * (1.f / 64.f);
        wgc[1] = mwB * (1.f / 64.f);
        wgc[2] = AA * (1.f / 64.f);
        wgc[3] = BBv * (1.f / 64.f);
        wgc[4] = AB * (2.f / 64.f);
    }
}

// ---------------------------------------------------------------- composite weights
__global__ __launch_bounds__(256) void k_prep_w2(
    const float* __restrict__ W1p, const float* __restrict__ Wk,
    const float* __restrict__ Wv, const float* __restrict__ bg,
    float* __restrict__ Wall, float* __restrict__ cu) {
    int flat = blockIdx.x * 256 + threadIdx.x;   // 64 blocks -> 16384
    int mat = flat >> 13, rem = flat & 8191;
    int o = rem >> 6, c = rem & 63;
    const float* Wm = mat ? Wv : Wk;
    float acc = 0.f;
    for (int d = 0; d < 64; d++)
        acc = fmaf(W1p[o * 64 + d], Wm[d * 64 + c], acc);
    Wall[flat] = acc;
    if (flat < 128) {
        float a = 0.f;
        for (int d = 0; d < 64; d++) a = fmaf(W1p[flat * 64 + d], bg[d], a);
        cu[flat] = a;
    }
}

// ---------------------------------------------------------------- W fragments (fp16 hi/lo)
__global__ __launch_bounds__(256) void k_prep_frag(
    const float* __restrict__ Wall, const float* __restrict__ Wk,
    const float* __restrict__ Wv,
    _Float16* __restrict__ cwh, _Float16* __restrict__ cwl,
    _Float16* __restrict__ mwh, _Float16* __restrict__ mwl) {
    int idx = blockIdx.x * 256 + threadIdx.x;    // grid 12 -> 3072
    if (idx < 2048) {
        int f = idx >> 6, lane = idx & 63;       // f = m*16 + ot*2 + ks
        int m = f >> 4, rest = f & 15;
        int ot = rest >> 1, ks = rest & 1;
        int o = ot * 16 + (lane & 15);
        int k0 = ks * 32 + (lane >> 4) * 8;
        const float* src = Wall + m * 8192 + o * 64 + k0;
        #pragma unroll
        for (int j = 0; j < 8; j++) {
            _Float16 h, l;
            split_fp16(src[j], h, l);
            cwh[(size_t)f * 512 + lane * 8 + j] = h;
            cwl[(size_t)f * 512 + lane * 8 + j] = l;
        }
    } else if (idx < 3072) {
        int id2 = idx - 2048;
        int f = id2 >> 6, lane = id2 & 63;       // f = m*8 + ot*2 + ks
        int m = f >> 3, rest = f & 7;
        int ot = rest >> 1, ks = rest & 1;
        int o = ot * 16 + (lane & 15);
        int k0 = ks * 32 + (lane >> 4) * 8;
        const float* src = (m ? Wv : Wk) + o * 64 + k0;
        #pragma unroll
        for (int j = 0; j < 8; j++) {
            _Float16 h, l;
            split_fp16(src[j], h, l);
            mwh[(size_t)f * 512 + lane * 8 + j] = h;
            mwl[(size_t)f * 512 + lane * 8 + j] = l;
        }
    }
}

// ---------------------------------------------------------------- MFMA prep: uk/uv + moments
// grid (1024, 2), 256 thr; no LDS (C-frag stored direct, 4x64B segments)
__global__ __launch_bounds__(256) void k_prep_mfma(
    const float* __restrict__ inp,
    const _Float16* __restrict__ cwh, const _Float16* __restrict__ cwl,
    const _Float16* __restrict__ mwh, const _Float16* __restrict__ mwl,
    const float* __restrict__ cu, const float* __restrict__ bg,
    const float* __restrict__ Wg,
    float* __restrict__ uk, float* __restrict__ uv,
    float* __restrict__ kaux, float* __restrict__ vaux, float* __restrict__ gbuf) {
    int tid = threadIdx.x;
    int wv = tid >> 6, lane = tid & 63;
    int quad = lane >> 4, col = lane & 15;
    int mat = blockIdx.y;
    int rowTile = blockIdx.x * 64 + wv * 16;
    half8 ah[2], al[2];
    {
        int rA = rowTile + col;
        const float* rp = inp + (size_t)rA * CIN + quad * 8;
        #pragma unroll
        for (int ks = 0; ks < 2; ks++) {
            H8 h, l;
            #pragma unroll
            for (int q = 0; q < 4; q++) {
                float2 v = *(const float2*)(rp + ks * 32 + 2 * q);
                split_fp16(v.x, h.u[2 * q], l.u[2 * q]);
                split_fp16(v.y, h.u[2 * q + 1], l.u[2 * q + 1]);
            }
            ah[ks] = h.v; al[ks] = l.v;
        }
    }
    const _Float16* cwhm = cwh + (size_t)mat * 16 * 512;
    const _Float16* cwlm = cwl + (size_t)mat * 16 * 512;
    float* dst = mat ? uv : uk;
    float* outb = dst + (size_t)(rowTile + quad * 4) * 128 + col;
    #pragma unroll
    for (int ot = 0; ot < 8; ot++) {
        f32x4 acc1 = {0.f, 0.f, 0.f, 0.f}, acc2 = {0.f, 0.f, 0.f, 0.f};
        #pragma unroll
        for (int ks = 0; ks < 2; ks++) {
            half8 bh = *(const half8*)(cwhm + (size_t)(ot * 2 + ks) * 512 + lane * 8);
            half8 bl = *(const half8*)(cwlm + (size_t)(ot * 2 + ks) * 512 + lane * 8);
            acc1 = __builtin_amdgcn_mfma_f32_16x16x32_f16(ah[ks], bh, acc1, 0, 0, 0);
            acc2 = __builtin_amdgcn_mfma_f32_16x16x32_f16(al[ks], bh, acc2, 0, 0, 0);
            acc2 = __builtin_amdgcn_mfma_f32_16x16x32_f16(ah[ks], bl, acc2, 0, 0, 0);
        }
        float cuv = cu[ot * 16 + col];
        #pragma unroll
        for (int r = 0; r < 4; r++)
            outb[(size_t)r * 128 + ot * 16] = fmaf(acc2[r], LO_INV, acc1[r]) + cuv;
    }
    const _Float16* mwhm = mwh + (size_t)mat * 8 * 512;
    const _Float16* mwlm = mwl + (size_t)mat * 8 * 512;
    float mk[4] = {0.f, 0.f, 0.f, 0.f}, kk2[4] = {0.f, 0.f, 0.f, 0.f};
    float kA[4] = {0.f, 0.f, 0.f, 0.f}, kB[4] = {0.f, 0.f, 0.f, 0.f};
    #pragma unroll
    for (int ot = 0; ot < 4; ot++) {
        f32x4 acc1 = {0.f, 0.f, 0.f, 0.f}, acc2 = {0.f, 0.f, 0.f, 0.f};
        #pragma unroll
        for (int ks = 0; ks < 2; ks++) {
            half8 bh = *(const half8*)(mwhm + (size_t)(ot * 2 + ks) * 512 + lane * 8);
            half8 bl = *(const half8*)(mwlm + (size_t)(ot * 2 + ks) * 512 + lane * 8);
            acc1 = __builtin_amdgcn_mfma_f32_16x16x32_f16(ah[ks], bh, acc1, 0, 0, 0);
            acc2 = __builtin_amdgcn_mfma_f32_16x16x32_f16(al[ks], bh, acc2, 0, 0, 0);
            acc2 = __builtin_amdgcn_mfma_f32_16x16x32_f16(ah[ks], bl, acc2, 0, 0, 0);
        }
        int o = ot * 16 + col;
        float bgo = bg[o], wa = Wg[2 * o], wb = Wg[2 * o + 1];
        #pragma unroll
        for (int r = 0; r < 4; r++) {
            float x = fmaf(acc2[r], LO_INV, acc1[r]) + bgo;
            mk[r] += x; kk2[r] = fmaf(x, x, kk2[r]);
            kA[r] = fmaf(x, wa, kA[r]); kB[r] = fmaf(x, wb, kB[r]);
        }
    }
    #pragma unroll
    for (int off = 1; off <= 8; off <<= 1) {
        #pragma unroll
        for (int r = 0; r < 4; r++) {
            mk[r] += __shfl_xor(mk[r], off, 64);
            kk2[r] += __shfl_xor(kk2[r], off, 64);
            kA[r] += __shfl_xor(kA[r], off, 64);
            kB[r] += __shfl_xor(kB[r], off, 64);
        }
    }
    float* aux = mat ? vaux : kaux;
    if (col == 0) {
        #pragma unroll
        for (int r = 0; r < 4; r++) {
            int row = rowTile + quad * 4 + r;
            float2 g = *(const float2*)(inp + (size_t)row * CIN + 64);
            float4 m1 = {mk[r] * (1.f / 64.f), kk2[r] * (1.f / 64.f),
                         kA[r] * (1.f / 32.f), kB[r] * (1.f / 32.f)};
            float4 m2 = {g.x, g.y, 0.f, 0.f};
            *(float4*)(aux + (size_t)row * 8) = m1;
            *(float4*)(aux + (size_t)row * 8 + 4) = m2;
            if (mat == 0) {
                float2 gw = {g.x, g.y};
                *(float2*)(gbuf + (size_t)row * 2) = gw;
            }
        }
    }
}

// ---------------------------------------------------------------- slot_prep: w2q, qb2
__global__ __launch_bounds__(512) void k_slot_prep(
    const float* __restrict__ slots, const float* __restrict__ lsg,
    const float* __restrict__ lsb, const float* __restrict__ Wq,
    const float* __restrict__ W2, const float* __restrict__ b2,
    float* __restrict__ w2q, float* __restrict__ qb2) {
    __shared__ float sn[512];
    __shared__ float qv[SS][64];
    __shared__ float wsum[8], wsum2[8];
    int b = blockIdx.x, t = threadIdx.x;
    int s = t >> 6, c = t & 63;
    float x = slots[(b * SS + s) * DD + c];
    float sum = x;
    for (int off = 32; off; off >>= 1) sum += __shfl_xor(sum, off, 64);
    float m = sum * (1.f / 64.f);
    float dv = x - m;
    float vs = dv * dv;
    for (int off = 32; off; off >>= 1) vs += __shfl_xor(vs, off, 64);
    float y = dv * rsqrtf(vs * (1.f / 64.f) + LN_EPS_F) * lsg[c] + lsb[c];
    float s1 = y, s2 = y * y;
    for (int off = 32; off; off >>= 1) { s1 += __shfl_xor(s1, off, 64); s2 += __shfl_xor(s2, off, 64); }
    if (c == 0) { wsum[s] = s1; wsum2[s] = s2; }
    __syncthreads();
    float ts1 = 0.f, ts2 = 0.f;
    #pragma unroll
    for (int i = 0; i < 8; i++) { ts1 += wsum[i]; ts2 += wsum2[i]; }
    float gm = ts1 * (1.f / 512.f);
    float gv = ts2 * (1.f / 512.f) - gm * gm;
    sn[t] = (y - gm) * rsqrtf(gv + LN_EPS_F);
    __syncthreads();
    float acc = 0.f;
    for (int j4 = 0; j4 < 64; j4 += 4)
        acc += dot4(*(const float4*)&sn[s * 64 + j4], *(const float4*)(Wq + c * 64 + j4));
    qv[s][c] = acc;
    __syncthreads();
    float a0 = 0.f, a1 = 0.f;
    for (int cc = 0; cc < 64; cc++) {
        float qc = qv[s][cc];
        a0 = fmaf(qc, W2[cc * DHH + c], a0);
        a1 = fmaf(qc, W2[cc * DHH + c + 64], a1);
    }
    w2q[(b * SS + s) * DHH + c] = a0 * QSCALE;
    w2q[(b * SS + s) * DHH + c + 64] = a1 * QSCALE;
    float qb = qv[s][c] * b2[c];
    for (int off = 32; off; off >>= 1) qb += __shfl_xor(qb, off, 64);
    if (c == 0) qb2[b * SS + s] = qb * QSCALE;
}

// ---------------------------------------------------------------- pass1: dots (depth-2 prefetch)
// Loads for step st+2 issued while computing st: ~800cy prefetch distance
// covers L3 latency. (256,4) raises VGPR cap to 128 (live ~75-90, no spill).
__global__ __launch_bounds__(256, 4) void k_pass1(
    const float* __restrict__ uk, const float* __restrict__ kaux,
    const float* __restrict__ positions, const float* __restrict__ scales,
    const float* __restrict__ avec, const float* __restrict__ bvec,
    const float* __restrict__ s1vec, const float* __restrict__ b1p,
    const float* __restrict__ wgc, const float* __restrict__ w2q,
    const float* __restrict__ qb2, float* __restrict__ dots) {
    int tid = threadIdx.x;
    int chunk = blockIdx.x, b = blockIdx.y;
    int wv = tid >> 6, lane = tid & 63, rh = lane >> 5, ol = lane & 31;
    int o4 = ol * 4;
    float4 a4 = *(const float4*)(avec + o4);
    float4 bv4 = *(const float4*)(bvec + o4);
    float4 s14 = *(const float4*)(s1vec + o4);
    float4 b14 = *(const float4*)(b1p + o4);
    float mwA = wgc[0], mwB = wgc[1], AA = wgc[2], BBc = wgc[3], AB2 = wgc[4];
    float p0[8], p1[8], rc0[8], rc1[8], qb[8];
    float4 wq[8];
    #pragma unroll
    for (int s = 0; s < 8; s++) {
        int bs = b * 8 + s;
        p0[s] = positions[bs * 2]; p1[s] = positions[bs * 2 + 1];
        rc0[s] = 1.f / scales[bs * 2]; rc1[s] = 1.f / scales[bs * 2 + 1];
        qb[s] = qb2[bs];
        wq[s] = *(const float4*)(w2q + (size_t)bs * DHH + o4);
    }
    int row0 = chunk * 64 + wv * 16 + rh;
    size_t rg = (size_t)b * NN + row0;
    float4 c1 = *(const float4*)(kaux + rg * 8);
    float4 c2 = *(const float4*)(kaux + rg * 8 + 4);
    float4 cu = *(const float4*)(uk + rg * 128 + o4);
    float4 d1 = *(const float4*)(kaux + (rg + 2) * 8);
    float4 d2 = *(const float4*)(kaux + (rg + 2) * 8 + 4);
    float4 du = *(const float4*)(uk + (rg + 2) * 128 + o4);
    for (int st = 0; st < 8; st++) {
        float4 e1, e2, eu;
        if (st < 6) {
            size_t rgn = rg + (size_t)(st + 2) * 2;
            e1 = *(const float4*)(kaux + rgn * 8);
            e2 = *(const float4*)(kaux + rgn * 8 + 4);
            eu = *(const float4*)(uk + rgn * 128 + o4);
        }
        int row = row0 + st * 2;
        #pragma unroll
        for (int s = 0; s < 8; s++) {
            float rel0 = (c2.x - p0[s]) * rc0[s];
            float rel1 = (c2.y - p1[s]) * rc1[s];
            float m = fmaf(rel1, mwB, fmaf(rel0, mwA, c1.x));
            float q2 = fmaf(rel0, fmaf(rel0, AA, c1.z), c1.y);
            q2 = fmaf(rel1, fmaf(rel1, BBc, c1.w), q2);
            q2 = fmaf(rel0 * rel1, AB2, q2);
            float var = fmaf(-m, m, q2);
            float rstd = rsqrtf(fmaxf(var, 0.f) + LN_EPS_F);
            float p = 0.f, t, h;
            t = fmaf(-m, s14.x, cu.x); t = fmaf(rel0, a4.x, t); t = fmaf(rel1, bv4.x, t);
            h = fmaf(rstd, t, b14.x); p = fmaf(fmaxf(h, 0.f), wq[s].x, p);
            t = fmaf(-m, s14.y, cu.y); t = fmaf(rel0, a4.y, t); t = fmaf(rel1, bv4.y, t);
            h = fmaf(rstd, t, b14.y); p = fmaf(fmaxf(h, 0.f), wq[s].y, p);
            t = fmaf(-m, s14.z, cu.z); t = fmaf(rel0, a4.z, t); t = fmaf(rel1, bv4.z, t);
            h = fmaf(rstd, t, b14.z); p = fmaf(fmaxf(h, 0.f), wq[s].z, p);
            t = fmaf(-m, s14.w, cu.w); t = fmaf(rel0, a4.w, t); t = fmaf(rel1, bv4.w, t);
            h = fmaf(rstd, t, b14.w); p = fmaf(fmaxf(h, 0.f), wq[s].w, p);
            p += __shfl_xor(p, 1, 64);
            p += __shfl_xor(p, 2, 64);
            p += __shfl_xor(p, 4, 64);
            p += __shfl_xor(p, 8, 64);
            p += __shfl_xor(p, 16, 64);
            if (ol == 0)
                dots[(size_t)(b * 8 + s) * NN + row] = p + qb[s];
        }
        c1 = d1; c2 = d2; cu = du;
        d1 = e1; d2 = e2; du = eu;
    }
}

// ---------------------------------------------------------------- pass2: H (depth-2 prefetch)
__global__ __launch_bounds__(256, 4) void k_pass2(
    const float* __restrict__ uv, const float* __restrict__ vaux,
    const float* __restrict__ positions, const float* __restrict__ scales,
    const float* __restrict__ avec, const float* __restrict__ bvec,
    const float* __restrict__ s1vec, const float* __restrict__ b1p,
    const float* __restrict__ wgc, const float* __restrict__ attn,
    float* __restrict__ H) {
    __shared__ float Hw[4 * 1024];
    int tid = threadIdx.x;
    int chunk = blockIdx.x, b = blockIdx.y;
    int wv = tid >> 6, lane = tid & 63, rh = lane >> 5, ol = lane & 31;
    int o4 = ol * 4;
    float4 a4 = *(const float4*)(avec + o4);
    float4 bv4 = *(const float4*)(bvec + o4);
    float4 s14 = *(const float4*)(s1vec + o4);
    float4 b14 = *(const float4*)(b1p + o4);
    float mwA = wgc[0], mwB = wgc[1], AA = wgc[2], BBc = wgc[3], AB2 = wgc[4];
    float p0[8], p1[8], rc0[8], rc1[8];
    #pragma unroll
    for (int s = 0; s < 8; s++) {
        int bs = b * 8 + s;
        p0[s] = positions[bs * 2]; p1[s] = positions[bs * 2 + 1];
        rc0[s] = 1.f / scales[bs * 2]; rc1[s] = 1.f / scales[bs * 2 + 1];
    }
    float hq[8][4];
    #pragma unroll
    for (int s = 0; s < 8; s++)
        #pragma unroll
        for (int c = 0; c < 4; c++) hq[s][c] = 0.f;
    int row0 = chunk * 64 + wv * 16 + rh;
    size_t rg = (size_t)b * NN + row0;
    float4 c1 = *(const float4*)(vaux + rg * 8);
    float4 c2 = *(const float4*)(vaux + rg * 8 + 4);
    float4 cu = *(const float4*)(uv + rg * 128 + o4);
    float4 d1 = *(const float4*)(vaux + (rg + 2) * 8);
    float4 d2 = *(const float4*)(vaux + (rg + 2) * 8 + 4);
    float4 du = *(const float4*)(uv + (rg + 2) * 128 + o4);
    for (int st = 0; st < 8; st++) {
        float4 e1, e2, eu;
        if (st < 6) {
            size_t rgn = rg + (size_t)(st + 2) * 2;
            e1 = *(const float4*)(vaux + rgn * 8);
            e2 = *(const float4*)(vaux + rgn * 8 + 4);
            eu = *(const float4*)(uv + rgn * 128 + o4);
        }
        int row = row0 + st * 2;
        #pragma unroll
        for (int s = 0; s < 8; s++) {
            float ar = attn[(size_t)(b * 8 + s) * NN + row];
            float rel0 = (c2.x - p0[s]) * rc0[s];
            float rel1 = (c2.y - p1[s]) * rc1[s];
            float m = fmaf(rel1, mwB, fmaf(rel0, mwA, c1.x));
            float q2 = fmaf(rel0, fmaf(rel0, AA, c1.z), c1.y);
            q2 = fmaf(rel1, fmaf(rel1, BBc, c1.w), q2);
            q2 = fmaf(rel0 * rel1, AB2, q2);
            float var = fmaf(-m, m, q2);
            float rstd = rsqrtf(fmaxf(var, 0.f) + LN_EPS_F);
            float t, h;
            t = fmaf(-m, s14.x, cu.x); t = fmaf(rel0, a4.x, t); t = fmaf(rel1, bv4.x, t);
            h = fmaf(rstd, t, b14.x); hq[s][0] = fmaf(ar, fmaxf(h, 0.f), hq[s][0]);
            t = fmaf(-m, s14.y, cu.y); t = fmaf(rel0, a4.y, t); t = fmaf(rel1, bv4.y, t);
            h = fmaf(rstd, t, b14.y); hq[s][1] = fmaf(ar, fmaxf(h, 0.f), hq[s][1]);
            t = fmaf(-m, s14.z, cu.z); t = fmaf(rel0, a4.z, t); t = fmaf(rel1, bv4.z, t);
            h = fmaf(rstd, t, b14.z); hq[s][2] = fmaf(ar, fmaxf(h, 0.f), hq[s][2]);
            t = fmaf(-m, s14.w, cu.w); t = fmaf(rel0, a4.w, t); t = fmaf(rel1, bv4.w, t);
            h = fmaf(rstd, t, b14.w); hq[s][3] = fmaf(ar, fmaxf(h, 0.f), hq[s][3]);
        }
        c1 = d1; c2 = d2; cu = du;
        d1 = e1; d2 = e2; du = eu;
    }
    #pragma unroll
    for (int s = 0; s < 8; s++)
        #pragma unroll
        for (int c = 0; c < 4; c++)
            hq[s][c] += __shfl_xor(hq[s][c], 32, 64);
    if (lane < 32) {
        #pragma unroll
        for (int s = 0; s < 8; s++) {
            float4 st = {hq[s][0], hq[s][1], hq[s][2], hq[s][3]};
            *(float4*)(Hw + wv * 1024 + s * 128 + o4) = st;
        }
    }
    __syncthreads();
    #pragma unroll
    for (int q = 0; q < 4; q++) {
        int flat = q * 256 + tid;
        float sum = Hw[flat] + Hw[1024 + flat] + Hw[2048 + flat] + Hw[3072 + flat];
        atomicAdd(&H[(size_t)b * 8 * DHH + flat], sum);
    }
}

// ---------------------------------------------------------------- softmax M,L (+zero H, sacc)
__global__ __launch_bounds__(256) void k_softmax_ms(
    const float* __restrict__ dots, float* __restrict__ Mv, float* __restrict__ Lv,
    float* __restrict__ H, float* __restrict__ sacc) {
    __shared__ float red[4];
    int bs = blockIdx.x, t = threadIdx.x;
    if (t < 128) H[(size_t)bs * DHH + t] = 0.f;
    if (t < 8) sacc[bs * 8 + t] = 0.f;
    const float* dp = dots + (size_t)bs * NN;
    float mx = -1e30f;
    #pragma unroll
    for (int it = 0; it < 4; it++) {
        float4 d = *(const float4*)(dp + it * 1024 + t * 4);
        mx = fmaxf(mx, fmaxf(fmaxf(d.x, d.y), fmaxf(d.z, d.w)));
    }
    for (int off = 32; off; off >>= 1) mx = fmaxf(mx, __shfl_xor(mx, off, 64));
    if ((t & 63) == 0) red[t >> 6] = mx;
    __syncthreads();
    float M = fmaxf(fmaxf(red[0], red[1]), fmaxf(red[2], red[3]));
    __syncthreads();
    float sm = 0.f;
    #pragma unroll
    for (int it = 0; it < 4; it++) {
        float4 d = *(const float4*)(dp + it * 1024 + t * 4);
        sm += __expf(d.x - M) + __expf(d.y - M) + __expf(d.z - M) + __expf(d.w - M);
    }
    for (int off = 32; off; off >>= 1) sm += __shfl_xor(sm, off, 64);
    if ((t & 63) == 0) red[t >> 6] = sm;
    __syncthreads();
    if (t == 0) { Mv[bs] = M; Lv[bs] = red[0] + red[1] + red[2] + red[3]; }
}

// ---------------------------------------------------------------- attn normalize + stats (fused)
template<bool WRITE_ATTN>
__global__ __launch_bounds__(256) void k_attn_stats(
    const float* __restrict__ dots, const float* __restrict__ Mv,
    const float* __restrict__ Lv, const float* __restrict__ gbuf,
    float* __restrict__ attn, float* __restrict__ sacc) {
    __shared__ float red[4][40];
    int chunk = blockIdx.x, b = blockIdx.y;
    int t = threadIdx.x;
    int n = chunk * 256 + t;
    float2 g = *(const float2*)(gbuf + (size_t)(b * NN + n) * 2);
    float gx2 = g.x * g.x, gy2 = g.y * g.y;
    float a[8];
    float rs = 0.f;
    #pragma unroll
    for (int s = 0; s < 8; s++) {
        int bs = b * 8 + s;
        float d = dots[(size_t)bs * NN + n];
        a[s] = __expf(d - Mv[bs]) * (1.f / Lv[bs]) + EPS_ATTN_F;
        rs += a[s];
    }
    float inv = 1.f / rs;
    float v[8][5];
    #pragma unroll
    for (int s = 0; s < 8; s++) {
        float av = a[s] * inv;
        if (WRITE_ATTN)
            attn[(size_t)(b * 8 + s) * NN + n] = av;
        v[s][0] = av;
        v[s][1] = av * g.x;  v[s][2] = av * g.y;
        v[s][3] = av * gx2;  v[s][4] = av * gy2;
    }
    #pragma unroll
    for (int off = 1; off <= 32; off <<= 1)
        #pragma unroll
        for (int s = 0; s < 8; s++)
            #pragma unroll
            for (int j = 0; j < 5; j++)
                v[s][j] += __shfl_xor(v[s][j], off, 64);
    int lane = t & 63, wv = t >> 6;
    if (lane == 0) {
        #pragma unroll
        for (int s = 0; s < 8; s++)
            #pragma unroll
            for (int j = 0; j < 5; j++)
                red[wv][s * 5 + j] = v[s][j];
    }
    __syncthreads();
    if (t < 40) {
        float sum = red[0][t] + red[1][t] + red[2][t] + red[3][t];
        int s = t / 5, j = t % 5;
        atomicAdd(&sacc[(b * 8 + s) * 8 + j], sum);
    }
}

// ---------------------------------------------------------------- GRU + slot MLP (+pos/scale finalize)
__global__ __launch_bounds__(64) void k_gru_mlp(
    const float* __restrict__ H, const float* __restrict__ sacc,
    const float* __restrict__ W2, const float* __restrict__ b2,
    const float* __restrict__ W_ih, const float* __restrict__ W_hh,
    const float* __restrict__ b_ih, const float* __restrict__ b_hh,
    const float* __restrict__ lmg, const float* __restrict__ lmb,
    const float* __restrict__ W3, const float* __restrict__ b3,
    const float* __restrict__ W4, const float* __restrict__ b4,
    float* __restrict__ slots, float* __restrict__ positions,
    float* __restrict__ scales) {
    int bs = blockIdx.x;
    int c = threadIdx.x;
    __shared__ float hl[DHH], ul[DD], sl[DD], yl[DD], hml[DHH];
    float A0 = sacc[bs * 8 + 0];
    if (c < 2) {
        float A1 = sacc[bs * 8 + 1 + c];
        float A2 = sacc[bs * 8 + 3 + c];
        positions[bs * 2 + c] = A1;
        float sx = A2 - A1 * A1 * (2.f - A0);
        scales[bs * 2 + c] = fminf(fmaxf(sqrtf(fmaxf(sx, 0.f)), 1e-3f), 2.f);
    }
    hl[c] = H[bs * DHH + c];
    hl[c + 64] = H[bs * DHH + 64 + c];
    float hold = slots[bs * DD + c];
    sl[c] = hold;
    __syncthreads();
    float u = A0 * b2[c];
    for (int o = 0; o < DHH; o += 4) {
        float4 w = *(const float4*)(W2 + c * DHH + o);
        u = fmaf(w.x, hl[o], fmaf(w.y, hl[o + 1], fmaf(w.z, hl[o + 2], fmaf(w.w, hl[o + 3], u))));
    }
    ul[c] = u;
    __syncthreads();
    float gir = b_ih[c], giz = b_ih[64 + c], gin = b_ih[128 + c];
    float ghr = b_hh[c], ghz = b_hh[64 + c], ghn = b_hh[128 + c];
    for (int k4 = 0; k4 < DD; k4 += 4) {
        float4 uu = *(const float4*)(ul + k4);
        float4 hh = *(const float4*)(sl + k4);
        gir += dot4(uu, *(const float4*)(W_ih + c * DD + k4));
        giz += dot4(uu, *(const float4*)(W_ih + (64 + c) * DD + k4));
        gin += dot4(uu, *(const float4*)(W_ih + (128 + c) * DD + k4));
        ghr += dot4(hh, *(const float4*)(W_hh + c * DD + k4));
        ghz += dot4(hh, *(const float4*)(W_hh + (64 + c) * DD + k4));
        ghn += dot4(hh, *(const float4*)(W_hh + (128 + c) * DD + k4));
    }
    float rg = 1.f / (1.f + __expf(-(gir + ghr)));
    float zg = 1.f / (1.f + __expf(-(giz + ghz)));
    float ng = tanhf(gin + rg * ghn);
    float snew = (1.f - zg) * ng + zg * hold;
    float sum = snew;
    for (int off = 32; off; off >>= 1) sum += __shfl_xor(sum, off, 64);
    float m = sum * (1.f / 64.f);
    float dv = snew - m;
    float vv = dv * dv;
    for (int off = 32; off; off >>= 1) vv += __shfl_xor(vv, off, 64);
    yl[c] = dv * rsqrtf(vv * (1.f / 64.f) + LN_EPS_F) * lmg[c] + lmb[c];
    __syncthreads();
    float h0 = b3[c], h1 = b3[64 + c];
    for (int k4 = 0; k4 < DD; k4 += 4) {
        float4 yy = *(const float4*)(yl + k4);
        h0 += dot4(yy, *(const float4*)(W3 + c * DD + k4));
        h1 += dot4(yy, *(const float4*)(W3 + (64 + c) * DD + k4));
    }
    hml[c] = fmaxf(h0, 0.f);
    hml[64 + c] = fmaxf(h1, 0.f);
    __syncthreads();
    float outv = b4[c];
    for (int o4 = 0; o4 < DHH; o4 += 4) {
        float4 hm4 = *(const float4*)(hml + o4);
        outv += dot4(hm4, *(const float4*)(W4 + c * DHH + o4));
    }
    slots[bs * DD + c] = outv;
}

// ---------------------------------------------------------------- write out (pos/scales from sacc)
__global__ __launch_bounds__(256) void k_write_out(
    const float* __restrict__ slots, const float* __restrict__ sacc,
    float* __restrict__ out) {
    int tid = blockIdx.x * 256 + threadIdx.x;
    if (tid >= BB * SS * 68) return;
    int bs = tid / 68, c = tid % 68;
    float v;
    if (c < 64) {
        v = slots[bs * 64 + c];
    } else if (c < 66) {
        v = sacc[bs * 8 + 1 + (c - 64)];
    } else {
        int p = c - 66;
        float A0 = sacc[bs * 8 + 0];
        float A1 = sacc[bs * 8 + 1 + p];
        float A2 = sacc[bs * 8 + 3 + p];
        float sx = A2 - A1 * A1 * (2.f - A0);
        v = fminf(fmaxf(sqrtf(fmaxf(sx, 0.f)), 1e-3f), 2.f);
    }
    out[tid] = v;
}

// ---------------------------------------------------------------- launcher
extern "C" void kernel_launch(void* const* d_in, const int* in_sizes, int n_in,
                              void* d_out, int out_size, void* d_ws, size_t ws_size,
                              hipStream_t stream) {
    (void)in_sizes; (void)n_in; (void)out_size; (void)ws_size;
    const float* inp = (const float*)d_in[0];
    const float* slots_in = (const float*)d_in[1];
    const float* Wq = (const float*)d_in[2];
    const float* Wk = (const float*)d_in[3];
    const float* Wv = (const float*)d_in[4];
    const float* Wg = (const float*)d_in[5];
    const float* bg = (const float*)d_in[6];
    const float* lpg = (const float*)d_in[7];
    const float* lpb = (const float*)d_in[8];
    const float* W1 = (const float*)d_in[9];
    const float* b1 = (const float*)d_in[10];
    const float* W2 = (const float*)d_in[11];
    const float* b2 = (const float*)d_in[12];
    const float* W_ih = (const float*)d_in[13];
    const float* W_hh = (const float*)d_in[14];
    const float* b_ih = (const float*)d_in[15];
    const float* b_hh = (const float*)d_in[16];
    const float* lmg = (const float*)d_in[17];
    const float* lmb = (const float*)d_in[18];
    const float* W3 = (const float*)d_in[19];
    const float* b3 = (const float*)d_in[20];
    const float* W4 = (const float*)d_in[21];
    const float* b4 = (const float*)d_in[22];
    const float* lsg = (const float*)d_in[23];
    const float* lsb = (const float*)d_in[24];
    float* out = (float*)d_out;
    float* ws = (float*)d_ws;

    const size_t NR = (size_t)BB * NN;
    size_t o_uk = 0;
    size_t o_uv = o_uk + NR * 128;
    size_t o_kaux = o_uv + NR * 128;
    size_t o_vaux = o_kaux + NR * 8;
    size_t o_gbuf = o_vaux + NR * 8;
    size_t o_dots = o_gbuf + NR * 2;
    size_t o_attn = o_dots + NR * SS;
    size_t o_slots = o_attn + NR * SS;
    size_t o_pos = o_slots + BB * SS * DD;
    size_t o_scl = o_pos + BB * SS * 2;
    size_t o_w2q = o_scl + BB * SS * 2;
    size_t o_qb2 = o_w2q + BB * SS * DHH;
    size_t o_Mv = o_qb2 + BB * SS;
    size_t o_Lv = o_Mv + BB * SS;
    size_t o_H = o_Lv + BB * SS;
    size_t o_sacc = o_H + BB * SS * DHH;
    size_t o_W1p = o_sacc + BB * SS * 8;
    size_t o_avec = o_W1p + DHH * DD;
    size_t o_bvec = o_avec + DHH;
    size_t o_s1v = o_bvec + DHH;
    size_t o_b1p = o_s1v + DHH;
    size_t o_wgc = o_b1p + DHH;
    size_t o_Wall = o_wgc + 8;
    size_t o_cu = o_Wall + 2 * DHH * DD;
    size_t o_cwh = o_cu + DHH;            // 2*16*512 halfs = 8192 floats
    size_t o_cwl = o_cwh + 8192;
    size_t o_mwh = o_cwl + 8192;          // 2*8*512 halfs = 4096 floats
    size_t o_mwl = o_mwh + 4096;

    float* uk = ws + o_uk;
    float* uv = ws + o_uv;
    float* kaux = ws + o_kaux;
    float* vaux = ws + o_vaux;
    float* gbuf = ws + o_gbuf;
    float* dots = ws + o_dots;
    float* attn = ws + o_attn;
    float* slots = ws + o_slots;
    float* positions = ws + o_pos;
    float* scales = ws + o_scl;
    float* w2q = ws + o_w2q;
    float* qb2 = ws + o_qb2;
    float* Mv = ws + o_Mv;
    float* Lv = ws + o_Lv;
    float* H = ws + o_H;
    float* sacc = ws + o_sacc;
    float* W1p = ws + o_W1p;
    float* avec = ws + o_avec;
    float* bvec = ws + o_bvec;
    float* s1v = ws + o_s1v;
    float* b1p = ws + o_b1p;
    float* wgc = ws + o_wgc;
    float* Wall = ws + o_Wall;
    float* cu = ws + o_cu;
    _Float16* cwh = (_Float16*)(ws + o_cwh);
    _Float16* cwl = (_Float16*)(ws + o_cwl);
    _Float16* mwh = (_Float16*)(ws + o_mwh);
    _Float16* mwl = (_Float16*)(ws + o_mwl);

    k_init_slots<<<32, 256, 0, stream>>>(slots_in, slots, positions, scales);
    k_prep_w<<<1, 256, 0, stream>>>(W1, lpg, lpb, b1, Wg, W1p, avec, bvec, s1v, b1p, wgc);
    k_prep_w2<<<64, 256, 0, stream>>>(W1p, Wk, Wv, bg, Wall, cu);
    k_prep_frag<<<12, 256, 0, stream>>>(Wall, Wk, Wv, cwh, cwl, mwh, mwl);
    k_prep_mfma<<<dim3(1024, 2), 256, 0, stream>>>(inp, cwh, cwl, mwh, mwl,
                                                   cu, bg, Wg, uk, uv, kaux, vaux, gbuf);

    for (int it = 0; it <= NITERS; ++it) {
        k_slot_prep<<<BB, 512, 0, stream>>>(slots, lsg, lsb, Wq, W2, b2, w2q, qb2);
        k_pass1<<<dim3(64, BB), 256, 0, stream>>>(uk, kaux, positions, scales,
                                                  avec, bvec, s1v, b1p, wgc, w2q, qb2, dots);
        k_softmax_ms<<<BB * SS, 256, 0, stream>>>(dots, Mv, Lv, H, sacc);
        if (it < NITERS) {
            k_attn_stats<true><<<dim3(16, BB), 256, 0, stream>>>(dots, Mv, Lv, gbuf, attn, sacc);
            k_pass2<<<dim3(64, BB), 256, 0, stream>>>(uv, vaux, positions, scales,
                                                      avec, bvec, s1v, b1p, wgc, attn, H);
            k_gru_mlp<<<BB * SS, 64, 0, stream>>>(H, sacc, W2, b2, W_ih, W_hh, b_ih, b_hh,
                                                  lmg, lmb, W3, b3, W4, b4,
                                                  slots, positions, scales);
        } else {
            k_attn_stats<false><<<dim3(16, BB), 256, 0, stream>>>(dots, Mv, Lv, gbuf, attn, sacc);
        }
    }
    k_write_out<<<34, 256, 0, stream>>>(slots, sacc, out);
}